// Round 1
// baseline (16277.008 us; speedup 1.0000x reference)
//
#include <hip/hip_runtime.h>
#include <hip/hip_bf16.h>
#include <math.h>

#define NN 40000
#define DD 128
#define HH 8
#define CC 16
#define EE 640000
#define ET (EE + NN)   // 680000 edges incl self loops
#define GG 64
#define SLOPE 0.2f

__device__ inline void atomicMaxFloat(float* addr, float val) {
    if (val >= 0.f) atomicMax((int*)addr, __float_as_int(val));
    else            atomicMin((unsigned int*)addr, __float_as_uint(val));
}

struct F8 { float v[8]; };
__device__ inline F8 load8(const float* __restrict__ p) {
    F8 r;
    float4 x = *(const float4*)p;
    float4 y = *(const float4*)(p + 4);
    r.v[0]=x.x; r.v[1]=x.y; r.v[2]=x.z; r.v[3]=x.w;
    r.v[4]=y.x; r.v[5]=y.y; r.v[6]=y.z; r.v[7]=y.w;
    return r;
}

// out[M,128] = A[M,128] @ W[128,128] (+ bias). Block = 32 rows.
__global__ __launch_bounds__(256) void gemm128(const float* __restrict__ A,
                                               const float* __restrict__ W,
                                               const float* __restrict__ bias,
                                               float* __restrict__ out) {
    __shared__ float Ws[128][128];  // 64 KB
    __shared__ float As[32][128];   // 16 KB
    int t = threadIdx.x;
    int row0 = blockIdx.x * 32;
    {
        const float4* Wv = (const float4*)W;
        float4* Wsv = (float4*)&Ws[0][0];
        for (int i = t; i < 4096; i += 256) Wsv[i] = Wv[i];
        const float4* Av = (const float4*)(A + (size_t)row0 * 128);
        float4* Asv = (float4*)&As[0][0];
        for (int i = t; i < 1024; i += 256) Asv[i] = Av[i];
    }
    __syncthreads();
    int ty = t >> 5;   // 0..7  -> rows ty*4..+3
    int tx = t & 31;   // 0..31 -> cols tx*4..+3
    float acc[4][4] = {};
    for (int k = 0; k < 128; ++k) {
        float4 w = *(const float4*)&Ws[k][tx * 4];
        #pragma unroll
        for (int i = 0; i < 4; ++i) {
            float a = As[ty * 4 + i][k];
            acc[i][0] += a * w.x; acc[i][1] += a * w.y;
            acc[i][2] += a * w.z; acc[i][3] += a * w.w;
        }
    }
    #pragma unroll
    for (int i = 0; i < 4; ++i) {
        int r = row0 + ty * 4 + i;
        float4 o = make_float4(acc[i][0], acc[i][1], acc[i][2], acc[i][3]);
        if (bias) {
            float4 b = *(const float4*)&bias[tx * 4];
            o.x += b.x; o.y += b.y; o.z += b.z; o.w += b.w;
        }
        *(float4*)&out[(size_t)r * 128 + tx * 4] = o;
    }
}

// al_src/al_dst per (node, head)
__global__ void al_kernel(const float* __restrict__ h,
                          const float* __restrict__ a_src,
                          const float* __restrict__ a_dst,
                          float* __restrict__ al_s, float* __restrict__ al_d) {
    int i = blockIdx.x * blockDim.x + threadIdx.x;
    if (i >= NN * HH) return;
    int n = i >> 3, hd = i & 7;
    const float4* hv = (const float4*)(h + (size_t)n * 128 + hd * 16);
    const float4* sv = (const float4*)(a_src + hd * 16);
    const float4* dv = (const float4*)(a_dst + hd * 16);
    float ss = 0.f, sd = 0.f;
    #pragma unroll
    for (int j = 0; j < 4; ++j) {
        float4 hx = hv[j], a = sv[j], b = dv[j];
        ss += hx.x*a.x + hx.y*a.y + hx.z*a.z + hx.w*a.w;
        sd += hx.x*b.x + hx.y*b.y + hx.z*b.z + hx.w*b.w;
    }
    al_s[i] = ss; al_d[i] = sd;
}

__global__ void init_md(float* __restrict__ m, float* __restrict__ den) {
    int i = blockIdx.x * blockDim.x + threadIdx.x;
    if (i < NN * HH) { m[i] = -INFINITY; den[i] = 0.f; }
}

__global__ void edge_max(const int* __restrict__ ei,
                         const float* __restrict__ al_s,
                         const float* __restrict__ al_d,
                         float* __restrict__ m) {
    int e = blockIdx.x * blockDim.x + threadIdx.x;
    if (e >= ET) return;
    int s, d;
    if (e < EE) { s = ei[e]; d = ei[EE + e]; } else { s = d = e - EE; }
    F8 a = load8(al_s + (size_t)s * 8);
    F8 b = load8(al_d + (size_t)d * 8);
    #pragma unroll
    for (int k = 0; k < 8; ++k) {
        float v = a.v[k] + b.v[k];
        v = v >= 0.f ? v : SLOPE * v;
        atomicMaxFloat(&m[(size_t)d * 8 + k], v);
    }
}

__global__ void edge_den(const int* __restrict__ ei,
                         const float* __restrict__ al_s,
                         const float* __restrict__ al_d,
                         const float* __restrict__ m,
                         float* __restrict__ den) {
    int e = blockIdx.x * blockDim.x + threadIdx.x;
    if (e >= ET) return;
    int s, d;
    if (e < EE) { s = ei[e]; d = ei[EE + e]; } else { s = d = e - EE; }
    F8 a = load8(al_s + (size_t)s * 8);
    F8 b = load8(al_d + (size_t)d * 8);
    F8 mm = load8(m + (size_t)d * 8);
    #pragma unroll
    for (int k = 0; k < 8; ++k) {
        float v = a.v[k] + b.v[k];
        v = v >= 0.f ? v : SLOPE * v;
        atomicAdd(&den[(size_t)d * 8 + k], __expf(v - mm.v[k]));
    }
}

// one thread per (edge, head): 16 atomic adds
__global__ void edge_agg(const int* __restrict__ ei,
                         const float* __restrict__ al_s,
                         const float* __restrict__ al_d,
                         const float* __restrict__ m,
                         const float* __restrict__ den,
                         const float* __restrict__ h,
                         float* __restrict__ agg) {
    long long i = (long long)blockIdx.x * blockDim.x + threadIdx.x;
    if (i >= (long long)ET * 8) return;
    int e = (int)(i >> 3), hd = (int)(i & 7);
    int s, d;
    if (e < EE) { s = ei[e]; d = ei[EE + e]; } else { s = d = e - EE; }
    float v = al_s[(size_t)s * 8 + hd] + al_d[(size_t)d * 8 + hd];
    v = v >= 0.f ? v : SLOPE * v;
    float alpha = __expf(v - m[(size_t)d * 8 + hd]) / (den[(size_t)d * 8 + hd] + 1e-16f);
    const float4* hv = (const float4*)(h + (size_t)s * 128 + hd * 16);
    float* ob = agg + (size_t)d * 128 + hd * 16;
    #pragma unroll
    for (int j = 0; j < 4; ++j) {
        float4 hx = hv[j];
        atomicAdd(ob + j * 4 + 0, hx.x * alpha);
        atomicAdd(ob + j * 4 + 1, hx.y * alpha);
        atomicAdd(ob + j * 4 + 2, hx.z * alpha);
        atomicAdd(ob + j * 4 + 3, hx.w * alpha);
    }
}

// x = relu(LN(x + agg + bias) * gamma + beta), one wave per node
__global__ __launch_bounds__(256) void node_finalize(const float* __restrict__ x,
                                                     const float* __restrict__ agg,
                                                     const float* __restrict__ bias,
                                                     const float* __restrict__ gamma,
                                                     const float* __restrict__ beta,
                                                     float* __restrict__ xout) {
    int wave = (blockIdx.x * 256 + threadIdx.x) >> 6;
    int lane = threadIdx.x & 63;
    if (wave >= NN) return;
    size_t base = (size_t)wave * 128;
    float v0 = x[base + lane]      + agg[base + lane]      + bias[lane];
    float v1 = x[base + 64 + lane] + agg[base + 64 + lane] + bias[64 + lane];
    float sum = v0 + v1;
    #pragma unroll
    for (int off = 32; off; off >>= 1) sum += __shfl_xor(sum, off);
    float mu = sum * (1.f / 128.f);
    float d0 = v0 - mu, d1 = v1 - mu;
    float var = d0 * d0 + d1 * d1;
    #pragma unroll
    for (int off = 32; off; off >>= 1) var += __shfl_xor(var, off);
    float inv = rsqrtf(var * (1.f / 128.f) + 1e-5f);
    float o0 = (d0 * inv) * gamma[lane]      + beta[lane];
    float o1 = (d1 * inv) * gamma[64 + lane] + beta[64 + lane];
    xout[base + lane]      = fmaxf(o0, 0.f);
    xout[base + 64 + lane] = fmaxf(o1, 0.f);
}

// mean-pool stage 1: sorted batch -> per-block LDS accumulation
__global__ __launch_bounds__(256) void pool_kernel(const float* __restrict__ x,
                                                   const int* __restrict__ batch,
                                                   float* __restrict__ s,
                                                   float* __restrict__ cnt) {
    __shared__ float acc[2][8][128];
    __shared__ float accc[2][8];
    const int NPB = 250;
    int n0 = blockIdx.x * NPB;
    int nend = min(n0 + NPB, NN);
    int t = threadIdx.x;
    int col = t & 127, grp = t >> 7;
    int b0 = batch[n0];
    int span = batch[nend - 1] - b0 + 1;
    for (int i = t; i < 2 * 8 * 128; i += 256) ((float*)acc)[i] = 0.f;
    if (t < 16) ((float*)accc)[t] = 0.f;
    __syncthreads();
    if (span <= 8) {
        for (int n = n0 + grp; n < nend; n += 2) {
            int b = batch[n] - b0;
            acc[grp][b][col] += x[(size_t)n * 128 + col];
            if (col == 0) accc[grp][b] += 1.f;
        }
        __syncthreads();
        for (int i = t; i < span * 128; i += 256) {
            int b = i >> 7, c = i & 127;
            atomicAdd(&s[(size_t)(b0 + b) * 128 + c], acc[0][b][c] + acc[1][b][c]);
        }
        if (t < span) atomicAdd(&cnt[b0 + t], accc[0][t] + accc[1][t]);
    } else {
        for (int n = n0 + grp; n < nend; n += 2) {
            int b = batch[n];
            atomicAdd(&s[(size_t)b * 128 + col], x[(size_t)n * 128 + col]);
            if (col == 0) atomicAdd(&cnt[b], 1.f);
        }
    }
}

__global__ void finalize_out(const float* __restrict__ s,
                             const float* __restrict__ cnt,
                             float* __restrict__ out) {
    int i = blockIdx.x * blockDim.x + threadIdx.x;
    if (i < GG * DD) out[i] = s[i] / fmaxf(cnt[i >> 7], 1.f);
}

extern "C" void kernel_launch(void* const* d_in, const int* in_sizes, int n_in,
                              void* d_out, int out_size, void* d_ws, size_t ws_size,
                              hipStream_t stream) {
    const float* x_in   = (const float*)d_in[0];
    const int*   ei     = (const int*)d_in[1];
    const int*   batch  = (const int*)d_in[2];
    const float* W_in   = (const float*)d_in[3];
    const float* b_in   = (const float*)d_in[4];
    const float* W_l    = (const float*)d_in[5];
    const float* att_s  = (const float*)d_in[6];
    const float* att_d  = (const float*)d_in[7];
    const float* bias_l = (const float*)d_in[8];
    const float* gamma  = (const float*)d_in[9];
    const float* beta   = (const float*)d_in[10];
    float* out = (float*)d_out;

    float* ws    = (float*)d_ws;
    float* xbuf  = ws;                     // N*D
    float* hbuf  = xbuf + (size_t)NN * DD; // N*D
    float* al_s  = hbuf + (size_t)NN * DD; // N*H
    float* al_d  = al_s + (size_t)NN * HH;
    float* mbuf  = al_d + (size_t)NN * HH;
    float* den   = mbuf + (size_t)NN * HH;
    float* agg   = den  + (size_t)NN * HH; // N*D
    float* pool  = agg  + (size_t)NN * DD; // G*D
    float* cnt   = pool + (size_t)GG * DD; // G

    // x = x_in @ W_in + b_in
    gemm128<<<NN / 32, 256, 0, stream>>>(x_in, W_in, b_in, xbuf);

    for (int l = 0; l < 3; ++l) {
        gemm128<<<NN / 32, 256, 0, stream>>>(xbuf, W_l + (size_t)l * 128 * 128, nullptr, hbuf);
        al_kernel<<<(NN * HH + 255) / 256, 256, 0, stream>>>(hbuf, att_s + l * 128, att_d + l * 128, al_s, al_d);
        init_md<<<(NN * HH + 255) / 256, 256, 0, stream>>>(mbuf, den);
        hipMemsetAsync(agg, 0, (size_t)NN * DD * sizeof(float), stream);
        edge_max<<<(ET + 255) / 256, 256, 0, stream>>>(ei, al_s, al_d, mbuf);
        edge_den<<<(ET + 255) / 256, 256, 0, stream>>>(ei, al_s, al_d, mbuf, den);
        edge_agg<<<(ET * 8 + 255) / 256, 256, 0, stream>>>(ei, al_s, al_d, mbuf, den, hbuf, agg);
        node_finalize<<<NN / 4, 256, 0, stream>>>(xbuf, agg, bias_l + l * 128, gamma + l * 128, beta + l * 128, xbuf);
    }

    hipMemsetAsync(pool, 0, (size_t)(GG * DD + GG) * sizeof(float), stream);
    pool_kernel<<<160, 256, 0, stream>>>(xbuf, batch, pool, cnt);
    finalize_out<<<(GG * DD + 255) / 256, 256, 0, stream>>>(pool, cnt, out);
}

// Round 2
// 562.782 us; speedup vs baseline: 28.9224x; 28.9224x over previous
//
#include <hip/hip_runtime.h>
#include <hip/hip_bf16.h>
#include <math.h>

#define NN 40000
#define DD 128
#define HH 8
#define CC 16
#define EE 640000
#define ET (EE + NN)   // 680000 edges incl self loops
#define GG 64
#define SLOPE 0.2f
#define NB_SCAN ((NN + 255) / 256)   // 157

// ---------------- GEMM: out[M,128] = A[M,128] @ W[128,128] (+bias) ----------------
__global__ __launch_bounds__(256) void gemm128(const float* __restrict__ A,
                                               const float* __restrict__ W,
                                               const float* __restrict__ bias,
                                               float* __restrict__ out) {
    __shared__ float Ws[128][128];  // 64 KB
    __shared__ float As[32][128];   // 16 KB
    int t = threadIdx.x;
    int row0 = blockIdx.x * 32;
    {
        const float4* Wv = (const float4*)W;
        float4* Wsv = (float4*)&Ws[0][0];
        for (int i = t; i < 4096; i += 256) Wsv[i] = Wv[i];
        const float4* Av = (const float4*)(A + (size_t)row0 * 128);
        float4* Asv = (float4*)&As[0][0];
        for (int i = t; i < 1024; i += 256) Asv[i] = Av[i];
    }
    __syncthreads();
    int ty = t >> 5;   // 0..7  -> rows ty*4..+3
    int tx = t & 31;   // 0..31 -> cols tx*4..+3
    float acc[4][4] = {};
    for (int k = 0; k < 128; ++k) {
        float4 w = *(const float4*)&Ws[k][tx * 4];
        #pragma unroll
        for (int i = 0; i < 4; ++i) {
            float a = As[ty * 4 + i][k];
            acc[i][0] += a * w.x; acc[i][1] += a * w.y;
            acc[i][2] += a * w.z; acc[i][3] += a * w.w;
        }
    }
    #pragma unroll
    for (int i = 0; i < 4; ++i) {
        int r = row0 + ty * 4 + i;
        float4 o = make_float4(acc[i][0], acc[i][1], acc[i][2], acc[i][3]);
        if (bias) {
            float4 b = *(const float4*)&bias[tx * 4];
            o.x += b.x; o.y += b.y; o.z += b.z; o.w += b.w;
        }
        *(float4*)&out[(size_t)r * 128 + tx * 4] = o;
    }
}

// ---------------- attention logits per (node, head) ----------------
__global__ void al_kernel(const float* __restrict__ h,
                          const float* __restrict__ a_src,
                          const float* __restrict__ a_dst,
                          float* __restrict__ al_s, float* __restrict__ al_d) {
    int i = blockIdx.x * blockDim.x + threadIdx.x;
    if (i >= NN * HH) return;
    int n = i >> 3, hd = i & 7;
    const float4* hv = (const float4*)(h + (size_t)n * 128 + hd * 16);
    const float4* sv = (const float4*)(a_src + hd * 16);
    const float4* dv = (const float4*)(a_dst + hd * 16);
    float ss = 0.f, sd = 0.f;
    #pragma unroll
    for (int j = 0; j < 4; ++j) {
        float4 hx = hv[j], a = sv[j], b = dv[j];
        ss += hx.x*a.x + hx.y*a.y + hx.z*a.z + hx.w*a.w;
        sd += hx.x*b.x + hx.y*b.y + hx.z*b.z + hx.w*b.w;
    }
    al_s[i] = ss; al_d[i] = sd;
}

// ---------------- CSR build (dst-indexed), done once, reused for 3 layers ----------------
__global__ void k_count(const int* __restrict__ ei, int* __restrict__ deg) {
    int e = blockIdx.x * blockDim.x + threadIdx.x;
    if (e >= ET) return;
    int d = (e < EE) ? ei[EE + e] : (e - EE);
    atomicAdd(&deg[d], 1);
}

__global__ __launch_bounds__(256) void k_scan1(const int* __restrict__ deg,
                                               int* __restrict__ incl,
                                               int* __restrict__ bsum) {
    __shared__ int s[256];
    int t = threadIdx.x;
    int idx = blockIdx.x * 256 + t;
    int v = (idx < NN) ? deg[idx] : 0;
    s[t] = v; __syncthreads();
    for (int off = 1; off < 256; off <<= 1) {
        int u = (t >= off) ? s[t - off] : 0;
        __syncthreads();
        s[t] += u;
        __syncthreads();
    }
    if (idx < NN) incl[idx] = s[t];
    if (t == 255) bsum[blockIdx.x] = s[255];
}

__global__ __launch_bounds__(256) void k_scan2(int* __restrict__ bsum) {
    __shared__ int s[256];
    int t = threadIdx.x;
    int v = (t < NB_SCAN) ? bsum[t] : 0;
    s[t] = v; __syncthreads();
    for (int off = 1; off < 256; off <<= 1) {
        int u = (t >= off) ? s[t - off] : 0;
        __syncthreads();
        s[t] += u;
        __syncthreads();
    }
    if (t < NB_SCAN) bsum[t] = s[t];
}

__global__ __launch_bounds__(256) void k_scan3(const int* __restrict__ deg,
                                               const int* __restrict__ incl,
                                               const int* __restrict__ bsum,
                                               int* __restrict__ rowptr,
                                               int* __restrict__ cursor) {
    int idx = blockIdx.x * 256 + threadIdx.x;
    if (idx >= NN) return;
    int off = (blockIdx.x > 0) ? bsum[blockIdx.x - 1] : 0;
    int inc = incl[idx] + off;
    rowptr[idx + 1] = inc;
    cursor[idx] = inc - deg[idx];
    if (idx == 0) rowptr[0] = 0;
}

__global__ void k_fill(const int* __restrict__ ei,
                       int* __restrict__ cursor, int* __restrict__ col) {
    int e = blockIdx.x * blockDim.x + threadIdx.x;
    if (e >= ET) return;
    int s, d;
    if (e < EE) { s = ei[e]; d = ei[EE + e]; } else { s = d = e - EE; }
    int pos = atomicAdd(&cursor[d], 1);
    col[pos] = s;
}

// ---------------- fused GAT layer: softmax + gather + residual + LN + ReLU ----------------
// one wave (64 lanes) per dst node
__global__ __launch_bounds__(256) void gat_fused(const int* __restrict__ rowptr,
                                                 const int* __restrict__ col,
                                                 const float* __restrict__ al_s,
                                                 const float* __restrict__ al_d,
                                                 const float* __restrict__ h,
                                                 const float* __restrict__ bias,
                                                 const float* __restrict__ gamma,
                                                 const float* __restrict__ beta,
                                                 float* __restrict__ x) {
    int wave = (blockIdx.x * 256 + threadIdx.x) >> 6;
    int lane = threadIdx.x & 63;
    if (wave >= NN) return;
    const int d = wave;
    const int start = rowptr[d], end = rowptr[d + 1];
    const int h8 = lane & 7;       // head this lane evaluates logits for
    const int ec = lane >> 3;      // edge slot within chunk of 8
    const float ald = al_d[(size_t)d * 8 + h8];

    // pass 1: per-head max over incoming edges (8 edges x 8 heads in flight)
    float mymax = -INFINITY;
    for (int e = start + ec; e < end; e += 8) {
        float v = al_s[(size_t)col[e] * 8 + h8] + ald;
        v = v >= 0.f ? v : SLOPE * v;
        mymax = fmaxf(mymax, v);
    }
    mymax = fmaxf(mymax, __shfl_xor(mymax, 8));
    mymax = fmaxf(mymax, __shfl_xor(mymax, 16));
    mymax = fmaxf(mymax, __shfl_xor(mymax, 32));

    // pass 1b: softmax denominator
    float dsum = 0.f;
    for (int e = start + ec; e < end; e += 8) {
        float v = al_s[(size_t)col[e] * 8 + h8] + ald;
        v = v >= 0.f ? v : SLOPE * v;
        dsum += __expf(v - mymax);
    }
    dsum += __shfl_xor(dsum, 8);
    dsum += __shfl_xor(dsum, 16);
    dsum += __shfl_xor(dsum, 32);
    const float rden = 1.f / (dsum + 1e-16f);

    // pass 2: weighted gather. lane owns cols {lane, lane+64}
    const int q0 = lane >> 4;        // head of col lane      (0..3)
    const int q1 = 4 + (lane >> 4);  // head of col lane+64   (4..7)
    float acc0 = 0.f, acc1 = 0.f;
    for (int e = start; e < end; ++e) {
        int s = col[e];
        float v = al_s[(size_t)s * 8 + h8] + ald;
        v = v >= 0.f ? v : SLOPE * v;
        float alpha = __expf(v - mymax) * rden;
        float a0 = __shfl(alpha, q0);
        float a1 = __shfl(alpha, q1);
        acc0 += h[(size_t)s * 128 + lane] * a0;
        acc1 += h[(size_t)s * 128 + 64 + lane] * a1;
    }

    // epilogue: residual + bias, LayerNorm, ReLU
    size_t base = (size_t)d * 128;
    float v0 = x[base + lane] + acc0 + bias[lane];
    float v1 = x[base + 64 + lane] + acc1 + bias[64 + lane];
    float sum = v0 + v1;
    #pragma unroll
    for (int off = 32; off; off >>= 1) sum += __shfl_xor(sum, off);
    float mu = sum * (1.f / 128.f);
    float d0 = v0 - mu, d1 = v1 - mu;
    float var = d0 * d0 + d1 * d1;
    #pragma unroll
    for (int off = 32; off; off >>= 1) var += __shfl_xor(var, off);
    float inv = rsqrtf(var * (1.f / 128.f) + 1e-5f);
    float o0 = (d0 * inv) * gamma[lane] + beta[lane];
    float o1 = (d1 * inv) * gamma[64 + lane] + beta[64 + lane];
    x[base + lane]      = fmaxf(o0, 0.f);
    x[base + 64 + lane] = fmaxf(o1, 0.f);
}

// ---------------- mean pool over sorted batch ----------------
__global__ __launch_bounds__(256) void pool_kernel(const float* __restrict__ x,
                                                   const int* __restrict__ batch,
                                                   float* __restrict__ s,
                                                   float* __restrict__ cnt) {
    __shared__ float acc[2][8][128];
    __shared__ float accc[2][8];
    const int NPB = 250;
    int n0 = blockIdx.x * NPB;
    int nend = min(n0 + NPB, NN);
    int t = threadIdx.x;
    int col = t & 127, grp = t >> 7;
    int b0 = batch[n0];
    int span = batch[nend - 1] - b0 + 1;
    for (int i = t; i < 2 * 8 * 128; i += 256) ((float*)acc)[i] = 0.f;
    if (t < 16) ((float*)accc)[t] = 0.f;
    __syncthreads();
    if (span <= 8) {
        for (int n = n0 + grp; n < nend; n += 2) {
            int b = batch[n] - b0;
            acc[grp][b][col] += x[(size_t)n * 128 + col];
            if (col == 0) accc[grp][b] += 1.f;
        }
        __syncthreads();
        for (int i = t; i < span * 128; i += 256) {
            int b = i >> 7, c = i & 127;
            atomicAdd(&s[(size_t)(b0 + b) * 128 + c], acc[0][b][c] + acc[1][b][c]);
        }
        if (t < span) atomicAdd(&cnt[b0 + t], accc[0][t] + accc[1][t]);
    } else {
        for (int n = n0 + grp; n < nend; n += 2) {
            int b = batch[n];
            atomicAdd(&s[(size_t)b * 128 + col], x[(size_t)n * 128 + col]);
            if (col == 0) atomicAdd(&cnt[b], 1.f);
        }
    }
}

__global__ void finalize_out(const float* __restrict__ s,
                             const float* __restrict__ cnt,
                             float* __restrict__ out) {
    int i = blockIdx.x * blockDim.x + threadIdx.x;
    if (i < GG * DD) out[i] = s[i] / fmaxf(cnt[i >> 7], 1.f);
}

extern "C" void kernel_launch(void* const* d_in, const int* in_sizes, int n_in,
                              void* d_out, int out_size, void* d_ws, size_t ws_size,
                              hipStream_t stream) {
    const float* x_in   = (const float*)d_in[0];
    const int*   ei     = (const int*)d_in[1];
    const int*   batch  = (const int*)d_in[2];
    const float* W_in   = (const float*)d_in[3];
    const float* b_in   = (const float*)d_in[4];
    const float* W_l    = (const float*)d_in[5];
    const float* att_s  = (const float*)d_in[6];
    const float* att_d  = (const float*)d_in[7];
    const float* bias_l = (const float*)d_in[8];
    const float* gamma  = (const float*)d_in[9];
    const float* beta   = (const float*)d_in[10];
    float* out = (float*)d_out;

    float* ws    = (float*)d_ws;
    float* xbuf  = ws;                      // N*D
    float* hbuf  = xbuf + (size_t)NN * DD;  // N*D
    float* al_s  = hbuf + (size_t)NN * DD;  // N*H
    float* al_d  = al_s + (size_t)NN * HH;  // N*H
    float* pool  = al_d + (size_t)NN * HH;  // G*D
    float* cnt   = pool + (size_t)GG * DD;  // G
    int*   ibase = (int*)(cnt + GG);
    int*   deg     = ibase;                 // NN
    int*   incl    = deg + NN;              // NN
    int*   bsum    = incl + NN;             // 256
    int*   rowptr  = bsum + 256;            // NN+1
    int*   cursor  = rowptr + NN + 1;       // NN
    int*   col     = cursor + NN;           // ET

    // ---- build CSR (dst-indexed) once ----
    hipMemsetAsync(deg, 0, NN * sizeof(int), stream);
    k_count<<<(ET + 255) / 256, 256, 0, stream>>>(ei, deg);
    k_scan1<<<NB_SCAN, 256, 0, stream>>>(deg, incl, bsum);
    k_scan2<<<1, 256, 0, stream>>>(bsum);
    k_scan3<<<NB_SCAN, 256, 0, stream>>>(deg, incl, bsum, rowptr, cursor);
    k_fill<<<(ET + 255) / 256, 256, 0, stream>>>(ei, cursor, col);

    // ---- input projection ----
    gemm128<<<NN / 32, 256, 0, stream>>>(x_in, W_in, b_in, xbuf);

    // ---- 3 GAT layers ----
    for (int l = 0; l < 3; ++l) {
        gemm128<<<NN / 32, 256, 0, stream>>>(xbuf, W_l + (size_t)l * 128 * 128, nullptr, hbuf);
        al_kernel<<<(NN * HH + 255) / 256, 256, 0, stream>>>(hbuf, att_s + l * 128, att_d + l * 128, al_s, al_d);
        gat_fused<<<NN / 4, 256, 0, stream>>>(rowptr, col, al_s, al_d, hbuf,
                                              bias_l + l * 128, gamma + l * 128, beta + l * 128, xbuf);
    }

    // ---- mean pool ----
    hipMemsetAsync(pool, 0, (size_t)(GG * DD + GG) * sizeof(float), stream);
    pool_kernel<<<160, 256, 0, stream>>>(xbuf, batch, pool, cnt);
    finalize_out<<<(GG * DD + 255) / 256, 256, 0, stream>>>(pool, cnt, out);
}

// Round 3
// 405.409 us; speedup vs baseline: 40.1496x; 1.3882x over previous
//
#include <hip/hip_runtime.h>
#include <hip/hip_bf16.h>
#include <math.h>

#define NN 40000
#define DD 128
#define HH 8
#define CC 16
#define EE 640000
#define ET (EE + NN)   // 680000 edges incl self loops
#define GG 64
#define SLOPE 0.2f
#define NB_SCAN ((NN + 255) / 256)   // 157

typedef unsigned int uint;
typedef unsigned short ushort;

__device__ inline ushort f2bf(float f) {
    uint u = __float_as_uint(f);
    uint r = (u + 0x7fffu + ((u >> 16) & 1u)) >> 16;
    return (ushort)r;
}
__device__ inline float bf_lo(uint u) { return __uint_as_float(u << 16); }
__device__ inline float bf_hi(uint u) { return __uint_as_float(u & 0xffff0000u); }

// ---------------- GEMM: out[M,128] = A[M,128] @ W[128,128] (+bias) ----------------
__global__ __launch_bounds__(256) void gemm128(const float* __restrict__ A,
                                               const float* __restrict__ W,
                                               const float* __restrict__ bias,
                                               float* __restrict__ out) {
    __shared__ float Ws[128][128];  // 64 KB
    __shared__ float As[32][128];   // 16 KB
    int t = threadIdx.x;
    int row0 = blockIdx.x * 32;
    {
        const float4* Wv = (const float4*)W;
        float4* Wsv = (float4*)&Ws[0][0];
        for (int i = t; i < 4096; i += 256) Wsv[i] = Wv[i];
        const float4* Av = (const float4*)(A + (size_t)row0 * 128);
        float4* Asv = (float4*)&As[0][0];
        for (int i = t; i < 1024; i += 256) Asv[i] = Av[i];
    }
    __syncthreads();
    int ty = t >> 5;
    int tx = t & 31;
    float acc[4][4] = {};
    for (int k = 0; k < 128; ++k) {
        float4 w = *(const float4*)&Ws[k][tx * 4];
        #pragma unroll
        for (int i = 0; i < 4; ++i) {
            float a = As[ty * 4 + i][k];
            acc[i][0] += a * w.x; acc[i][1] += a * w.y;
            acc[i][2] += a * w.z; acc[i][3] += a * w.w;
        }
    }
    #pragma unroll
    for (int i = 0; i < 4; ++i) {
        int r = row0 + ty * 4 + i;
        float4 o = make_float4(acc[i][0], acc[i][1], acc[i][2], acc[i][3]);
        if (bias) {
            float4 b = *(const float4*)&bias[tx * 4];
            o.x += b.x; o.y += b.y; o.z += b.z; o.w += b.w;
        }
        *(float4*)&out[(size_t)r * 128 + tx * 4] = o;
    }
}

// ---------------- pack h->bf16 + attention logits per (node, head) ----------------
__global__ void pack_al(const float* __restrict__ h,
                        const float* __restrict__ a_src,
                        const float* __restrict__ a_dst,
                        float* __restrict__ al_s, float* __restrict__ al_d,
                        uint* __restrict__ h16) {
    int i = blockIdx.x * blockDim.x + threadIdx.x;
    if (i >= NN * HH) return;
    int n = i >> 3, hd = i & 7;
    const float4* hv = (const float4*)(h + (size_t)n * 128 + hd * 16);
    const float4* sv = (const float4*)(a_src + hd * 16);
    const float4* dv = (const float4*)(a_dst + hd * 16);
    float ss = 0.f, sd = 0.f;
    uint u[8];
    #pragma unroll
    for (int j = 0; j < 4; ++j) {
        float4 hx = hv[j], a = sv[j], b = dv[j];
        ss += hx.x*a.x + hx.y*a.y + hx.z*a.z + hx.w*a.w;
        sd += hx.x*b.x + hx.y*b.y + hx.z*b.z + hx.w*b.w;
        u[2*j]   = (uint)f2bf(hx.x) | ((uint)f2bf(hx.y) << 16);
        u[2*j+1] = (uint)f2bf(hx.z) | ((uint)f2bf(hx.w) << 16);
    }
    al_s[i] = ss; al_d[i] = sd;
    uint4* dst = (uint4*)(h16 + ((size_t)n << 6) + (hd << 3));
    dst[0] = make_uint4(u[0], u[1], u[2], u[3]);
    dst[1] = make_uint4(u[4], u[5], u[6], u[7]);
}

// ---------------- CSR build (dst-indexed) ----------------
__global__ void k_count(const int* __restrict__ ei, int* __restrict__ deg) {
    int e = blockIdx.x * blockDim.x + threadIdx.x;
    if (e >= ET) return;
    int d = (e < EE) ? ei[EE + e] : (e - EE);
    atomicAdd(&deg[d], 1);
}

__global__ __launch_bounds__(256) void k_scan1(const int* __restrict__ deg,
                                               int* __restrict__ incl,
                                               int* __restrict__ bsum) {
    __shared__ int s[256];
    int t = threadIdx.x;
    int idx = blockIdx.x * 256 + t;
    int v = (idx < NN) ? deg[idx] : 0;
    s[t] = v; __syncthreads();
    for (int off = 1; off < 256; off <<= 1) {
        int u = (t >= off) ? s[t - off] : 0;
        __syncthreads();
        s[t] += u;
        __syncthreads();
    }
    if (idx < NN) incl[idx] = s[t];
    if (t == 255) bsum[blockIdx.x] = s[255];
}

__global__ __launch_bounds__(256) void k_scan2(int* __restrict__ bsum) {
    __shared__ int s[256];
    int t = threadIdx.x;
    int v = (t < NB_SCAN) ? bsum[t] : 0;
    s[t] = v; __syncthreads();
    for (int off = 1; off < 256; off <<= 1) {
        int u = (t >= off) ? s[t - off] : 0;
        __syncthreads();
        s[t] += u;
        __syncthreads();
    }
    if (t < NB_SCAN) bsum[t] = s[t];
}

__global__ __launch_bounds__(256) void k_scan3(const int* __restrict__ deg,
                                               const int* __restrict__ incl,
                                               const int* __restrict__ bsum,
                                               int* __restrict__ rowptr,
                                               int* __restrict__ cursor) {
    int idx = blockIdx.x * 256 + threadIdx.x;
    if (idx >= NN) return;
    int off = (blockIdx.x > 0) ? bsum[blockIdx.x - 1] : 0;
    int inc = incl[idx] + off;
    rowptr[idx + 1] = inc;
    cursor[idx] = inc - deg[idx];
    if (idx == 0) rowptr[0] = 0;
}

__global__ void k_fill(const int* __restrict__ ei,
                       int* __restrict__ cursor, int* __restrict__ col) {
    int e = blockIdx.x * blockDim.x + threadIdx.x;
    if (e >= ET) return;
    int s, d;
    if (e < EE) { s = ei[e]; d = ei[EE + e]; } else { s = d = e - EE; }
    int pos = atomicAdd(&cursor[d], 1);
    col[pos] = s;
}

// ---------------- fused GAT layer ----------------
// one wave per dst node; bf16 message gather, 2 edges/iter
__global__ __launch_bounds__(256) void gat_fused(const int* __restrict__ rowptr,
                                                 const int* __restrict__ col,
                                                 const float* __restrict__ al_s,
                                                 const float* __restrict__ al_d,
                                                 const uint* __restrict__ h16,
                                                 const float* __restrict__ bias,
                                                 const float* __restrict__ gamma,
                                                 const float* __restrict__ beta,
                                                 float* __restrict__ x) {
    __shared__ float alph[4][64][8];   // 8 KB: exp-numerators per (edge, head)
    int wv = threadIdx.x >> 6;
    int wave = blockIdx.x * 4 + wv;
    int lane = threadIdx.x & 63;
    if (wave >= NN) return;
    const int d = wave;
    const int start = rowptr[d], end = rowptr[d + 1];
    const int deg = end - start;

    const int h8 = lane & 7;       // head this lane evaluates logits for
    const int ec = lane >> 3;      // edge slot within chunk of 8
    const int k  = lane & 31;      // col group: cols 4k..4k+3
    const int g  = lane >> 5;      // edge parity in pass 2
    const int myhead = k >> 2;

    float a0 = 0.f, a1 = 0.f, a2 = 0.f, a3 = 0.f;
    float r2;

    if (deg <= 64) {
        int col_r = 0;
        if (lane < deg) col_r = col[start + lane];

        // pass 1: logits for all edges, 8 edges x 8 heads per iteration
        float ev[8];
        float mymax = -INFINITY;
        #pragma unroll
        for (int i = 0; i < 8; ++i) {
            int j = ec + 8 * i;
            float v = -INFINITY;
            if (j < deg) {
                int s = __shfl(col_r, j);
                float t = al_s[(size_t)s * 8 + h8] + al_d[(size_t)d * 8 + h8];
                v = t >= 0.f ? t : SLOPE * t;
            }
            ev[i] = v;
            mymax = fmaxf(mymax, v);
        }
        mymax = fmaxf(mymax, __shfl_xor(mymax, 8));
        mymax = fmaxf(mymax, __shfl_xor(mymax, 16));
        mymax = fmaxf(mymax, __shfl_xor(mymax, 32));

        float dsum = 0.f;
        #pragma unroll
        for (int i = 0; i < 8; ++i) {
            int j = ec + 8 * i;
            float e = __expf(ev[i] - mymax);   // -inf -> 0
            if (j < deg) {
                alph[wv][j][h8] = e;
                dsum += e;
            }
        }
        dsum += __shfl_xor(dsum, 8);
        dsum += __shfl_xor(dsum, 16);
        dsum += __shfl_xor(dsum, 32);
        float rden = 1.f / (dsum + 1e-16f);
        r2 = __shfl(rden, myhead);

        // pass 2: gather bf16 rows, 2 edges per iteration across half-waves
        for (int j2 = g; j2 < deg; j2 += 2) {
            int s = __shfl(col_r, j2);
            float a = alph[wv][j2][myhead];
            uint2 hv = *((const uint2*)(h16 + ((size_t)s << 6)) + k);
            a0 += a * bf_lo(hv.x);
            a1 += a * bf_hi(hv.x);
            a2 += a * bf_lo(hv.y);
            a3 += a * bf_hi(hv.y);
        }
    } else {
        // generic fallback (deg > 64) — never expected at this graph size
        const float ald = al_d[(size_t)d * 8 + h8];
        float mymax = -INFINITY;
        for (int e = start + ec; e < end; e += 8) {
            float t = al_s[(size_t)col[e] * 8 + h8] + ald;
            t = t >= 0.f ? t : SLOPE * t;
            mymax = fmaxf(mymax, t);
        }
        mymax = fmaxf(mymax, __shfl_xor(mymax, 8));
        mymax = fmaxf(mymax, __shfl_xor(mymax, 16));
        mymax = fmaxf(mymax, __shfl_xor(mymax, 32));
        float dsum = 0.f;
        for (int e = start + ec; e < end; e += 8) {
            float t = al_s[(size_t)col[e] * 8 + h8] + ald;
            t = t >= 0.f ? t : SLOPE * t;
            dsum += __expf(t - mymax);
        }
        dsum += __shfl_xor(dsum, 8);
        dsum += __shfl_xor(dsum, 16);
        dsum += __shfl_xor(dsum, 32);
        float rden = 1.f / (dsum + 1e-16f);
        r2 = __shfl(rden, myhead);
        float m2 = __shfl(mymax, myhead);
        float aldh = al_d[(size_t)d * 8 + myhead];
        for (int j2 = g; j2 < deg; j2 += 2) {
            int s = col[start + j2];
            float t = al_s[(size_t)s * 8 + myhead] + aldh;
            t = t >= 0.f ? t : SLOPE * t;
            float a = __expf(t - m2);
            uint2 hv = *((const uint2*)(h16 + ((size_t)s << 6)) + k);
            a0 += a * bf_lo(hv.x);
            a1 += a * bf_hi(hv.x);
            a2 += a * bf_lo(hv.y);
            a3 += a * bf_hi(hv.y);
        }
    }

    a0 *= r2; a1 *= r2; a2 *= r2; a3 *= r2;
    // combine edge-parity halves
    float c0 = a0 + __shfl_xor(a0, 32);
    float c1 = a1 + __shfl_xor(a1, 32);
    float c2 = a2 + __shfl_xor(a2, 32);
    float c3 = a3 + __shfl_xor(a3, 32);
    float accA = g ? c2 : c0;
    float accB = g ? c3 : c1;

    // epilogue: residual + bias, LayerNorm, ReLU. lane owns cols 4k+2g, 4k+2g+1
    int colA = (k << 2) + (g << 1);
    size_t base = (size_t)d * 128;
    float2 xv = *(const float2*)(x + base + colA);
    float2 bv = *(const float2*)(bias + colA);
    float v0 = xv.x + accA + bv.x;
    float v1 = xv.y + accB + bv.y;
    float sum = v0 + v1;
    #pragma unroll
    for (int off = 32; off; off >>= 1) sum += __shfl_xor(sum, off);
    float mu = sum * (1.f / 128.f);
    float d0 = v0 - mu, d1 = v1 - mu;
    float var = d0 * d0 + d1 * d1;
    #pragma unroll
    for (int off = 32; off; off >>= 1) var += __shfl_xor(var, off);
    float inv = rsqrtf(var * (1.f / 128.f) + 1e-5f);
    float2 gv = *(const float2*)(gamma + colA);
    float2 btv = *(const float2*)(beta + colA);
    float o0 = (d0 * inv) * gv.x + btv.x;
    float o1 = (d1 * inv) * gv.y + btv.y;
    float2 o = make_float2(fmaxf(o0, 0.f), fmaxf(o1, 0.f));
    *(float2*)(x + base + colA) = o;
}

// ---------------- mean pool over sorted batch ----------------
__global__ __launch_bounds__(256) void pool_kernel(const float* __restrict__ x,
                                                   const int* __restrict__ batch,
                                                   float* __restrict__ s,
                                                   float* __restrict__ cnt) {
    __shared__ float acc[2][8][128];
    __shared__ float accc[2][8];
    const int NPB = 250;
    int n0 = blockIdx.x * NPB;
    int nend = min(n0 + NPB, NN);
    int t = threadIdx.x;
    int col = t & 127, grp = t >> 7;
    int b0 = batch[n0];
    int span = batch[nend - 1] - b0 + 1;
    for (int i = t; i < 2 * 8 * 128; i += 256) ((float*)acc)[i] = 0.f;
    if (t < 16) ((float*)accc)[t] = 0.f;
    __syncthreads();
    if (span <= 8) {
        for (int n = n0 + grp; n < nend; n += 2) {
            int b = batch[n] - b0;
            acc[grp][b][col] += x[(size_t)n * 128 + col];
            if (col == 0) accc[grp][b] += 1.f;
        }
        __syncthreads();
        for (int i = t; i < span * 128; i += 256) {
            int b = i >> 7, c = i & 127;
            atomicAdd(&s[(size_t)(b0 + b) * 128 + c], acc[0][b][c] + acc[1][b][c]);
        }
        if (t < span) atomicAdd(&cnt[b0 + t], accc[0][t] + accc[1][t]);
    } else {
        for (int n = n0 + grp; n < nend; n += 2) {
            int b = batch[n];
            atomicAdd(&s[(size_t)b * 128 + col], x[(size_t)n * 128 + col]);
            if (col == 0) atomicAdd(&cnt[b], 1.f);
        }
    }
}

__global__ void finalize_out(const float* __restrict__ s,
                             const float* __restrict__ cnt,
                             float* __restrict__ out) {
    int i = blockIdx.x * blockDim.x + threadIdx.x;
    if (i < GG * DD) out[i] = s[i] / fmaxf(cnt[i >> 7], 1.f);
}

extern "C" void kernel_launch(void* const* d_in, const int* in_sizes, int n_in,
                              void* d_out, int out_size, void* d_ws, size_t ws_size,
                              hipStream_t stream) {
    const float* x_in   = (const float*)d_in[0];
    const int*   ei     = (const int*)d_in[1];
    const int*   batch  = (const int*)d_in[2];
    const float* W_in   = (const float*)d_in[3];
    const float* b_in   = (const float*)d_in[4];
    const float* W_l    = (const float*)d_in[5];
    const float* att_s  = (const float*)d_in[6];
    const float* att_d  = (const float*)d_in[7];
    const float* bias_l = (const float*)d_in[8];
    const float* gamma  = (const float*)d_in[9];
    const float* beta   = (const float*)d_in[10];
    float* out = (float*)d_out;

    float* ws    = (float*)d_ws;
    float* xbuf  = ws;                      // N*D
    float* hbuf  = xbuf + (size_t)NN * DD;  // N*D
    float* al_s  = hbuf + (size_t)NN * DD;  // N*H
    float* al_d  = al_s + (size_t)NN * HH;  // N*H
    float* pool  = al_d + (size_t)NN * HH;  // G*D
    float* cnt   = pool + (size_t)GG * DD;  // G
    int*   ibase = (int*)(cnt + GG);
    int*   deg     = ibase;                 // NN
    int*   incl    = deg + NN;              // NN
    int*   bsum    = incl + NN;             // 256
    int*   rowptr  = bsum + 256;            // NN+1
    int*   cursor  = rowptr + NN + 1;       // NN
    int*   col     = cursor + NN;           // ET
    uint*  h16     = (uint*)(col + ET);     // N*64 uints (bf16 h)

    // ---- build CSR (dst-indexed) once ----
    hipMemsetAsync(deg, 0, NN * sizeof(int), stream);
    k_count<<<(ET + 255) / 256, 256, 0, stream>>>(ei, deg);
    k_scan1<<<NB_SCAN, 256, 0, stream>>>(deg, incl, bsum);
    k_scan2<<<1, 256, 0, stream>>>(bsum);
    k_scan3<<<NB_SCAN, 256, 0, stream>>>(deg, incl, bsum, rowptr, cursor);
    k_fill<<<(ET + 255) / 256, 256, 0, stream>>>(ei, cursor, col);

    // ---- input projection ----
    gemm128<<<NN / 32, 256, 0, stream>>>(x_in, W_in, b_in, xbuf);

    // ---- 3 GAT layers ----
    for (int l = 0; l < 3; ++l) {
        gemm128<<<NN / 32, 256, 0, stream>>>(xbuf, W_l + (size_t)l * 128 * 128, nullptr, hbuf);
        pack_al<<<(NN * HH + 255) / 256, 256, 0, stream>>>(hbuf, att_s + l * 128, att_d + l * 128, al_s, al_d, h16);
        gat_fused<<<NN / 4, 256, 0, stream>>>(rowptr, col, al_s, al_d, h16,
                                              bias_l + l * 128, gamma + l * 128, beta + l * 128, xbuf);
    }

    // ---- mean pool ----
    hipMemsetAsync(pool, 0, (size_t)(GG * DD + GG) * sizeof(float), stream);
    pool_kernel<<<160, 256, 0, stream>>>(xbuf, batch, pool, cnt);
    finalize_out<<<(GG * DD + 255) / 256, 256, 0, stream>>>(pool, cnt, out);
}

// Round 4
// 325.767 us; speedup vs baseline: 49.9652x; 1.2445x over previous
//
#include <hip/hip_runtime.h>
#include <hip/hip_bf16.h>
#include <math.h>

#define NN 40000
#define DD 128
#define HH 8
#define CC 16
#define EE 640000
#define ET (EE + NN)   // 680000 edges incl self loops
#define GG 64
#define SLOPE 0.2f
#define NB_SCAN ((NN + 255) / 256)   // 157

typedef unsigned int uint;
typedef unsigned short ushort;
typedef __attribute__((ext_vector_type(8))) short bf16x8;
typedef __attribute__((ext_vector_type(4))) float f32x4;

__device__ inline ushort f2bf(float f) {
    uint u = __float_as_uint(f);
    uint r = (u + 0x7fffu + ((u >> 16) & 1u)) >> 16;
    return (ushort)r;
}
__device__ inline float bf_lo(uint u) { return __uint_as_float(u << 16); }
__device__ inline float bf_hi(uint u) { return __uint_as_float(u & 0xffff0000u); }

// ---------------- one-time prep: W^T -> bf16, x_in -> bf16 ----------------
__global__ void prep_wt(const float* __restrict__ Win, const float* __restrict__ Wl,
                        ushort* __restrict__ wt) {
    int i = blockIdx.x * 256 + threadIdx.x;   // 4*128*128
    if (i >= 4 * 128 * 128) return;
    int w = i >> 14, rem = i & 16383, n = rem >> 7, k = rem & 127;
    const float* src = (w == 0) ? Win : (Wl + (size_t)(w - 1) * 16384);
    wt[i] = f2bf(src[k * 128 + n]);
}

__global__ void pack_x16(const float* __restrict__ x, ushort* __restrict__ x16) {
    int i = blockIdx.x * 256 + threadIdx.x;   // per 4 floats
    if (i >= NN * 32) return;
    float4 v = ((const float4*)x)[i];
    uint2 o;
    o.x = (uint)f2bf(v.x) | ((uint)f2bf(v.y) << 16);
    o.y = (uint)f2bf(v.z) | ((uint)f2bf(v.w) << 16);
    ((uint2*)x16)[i] = o;
}

// ---------------- MFMA bf16 GEMM: [64 rows/block] x 128 x 128 ----------------
// mode A (h16out != 0): write al_s/al_d + packed bf16 h16
// mode B: write xout fp32 (+bias) and x16out bf16
__global__ __launch_bounds__(256) void gemm_mfma(const ushort* __restrict__ A16,
                                                 const ushort* __restrict__ WT,
                                                 const float* __restrict__ bias,
                                                 const float* __restrict__ atts,
                                                 const float* __restrict__ attd,
                                                 float* __restrict__ xout,
                                                 ushort* __restrict__ x16out,
                                                 float* __restrict__ al_s,
                                                 float* __restrict__ al_d,
                                                 ushort* __restrict__ h16out) {
    __shared__ ushort lds[128 * 136];   // 34816 B; W^T padded; reused as f32 tile
    int t = threadIdx.x;
    int wv = t >> 6, l = t & 63;
    int row0 = blockIdx.x * 64;

    {   // stage W^T [128][128] bf16 into padded LDS rows of 136
        const uint4* src = (const uint4*)WT;
        for (int i = t; i < 2048; i += 256) {
            int r = i >> 4, c = i & 15;
            *(uint4*)((uint*)(lds + r * 136) + c * 4) = src[i];
        }
    }
    __syncthreads();

    int q = l >> 4, r16 = l & 15;
    const ushort* arow = A16 + (size_t)(row0 + wv * 16 + r16) * 128 + q * 8;
    bf16x8 a0 = *(const bf16x8*)(arow);
    bf16x8 a1 = *(const bf16x8*)(arow + 32);
    bf16x8 a2 = *(const bf16x8*)(arow + 64);
    bf16x8 a3 = *(const bf16x8*)(arow + 96);
    f32x4 acc[8];
    #pragma unroll
    for (int c = 0; c < 8; ++c) acc[c] = (f32x4){0.f, 0.f, 0.f, 0.f};
    #pragma unroll
    for (int c = 0; c < 8; ++c) {
        const ushort* bp = lds + (c * 16 + r16) * 136 + q * 8;
        bf16x8 b0 = *(const bf16x8*)(bp);
        bf16x8 b1 = *(const bf16x8*)(bp + 32);
        bf16x8 b2 = *(const bf16x8*)(bp + 64);
        bf16x8 b3 = *(const bf16x8*)(bp + 96);
        acc[c] = __builtin_amdgcn_mfma_f32_16x16x32_bf16(a0, b0, acc[c], 0, 0, 0);
        acc[c] = __builtin_amdgcn_mfma_f32_16x16x32_bf16(a1, b1, acc[c], 0, 0, 0);
        acc[c] = __builtin_amdgcn_mfma_f32_16x16x32_bf16(a2, b2, acc[c], 0, 0, 0);
        acc[c] = __builtin_amdgcn_mfma_f32_16x16x32_bf16(a3, b3, acc[c], 0, 0, 0);
    }
    __syncthreads();   // all waves done reading W^T

    // stage acc to per-wave fp32 tile [16][132]
    float* tile = (float*)lds + wv * (16 * 132);
    #pragma unroll
    for (int c = 0; c < 8; ++c)
        #pragma unroll
        for (int i = 0; i < 4; ++i)
            tile[(q * 4 + i) * 132 + c * 16 + r16] = acc[c][i];
    __syncthreads();

    // epilogue: 2 (row,head) units per lane; row = u&15, head = u>>4 (+uu*4)
    #pragma unroll
    for (int uu = 0; uu < 2; ++uu) {
        int u = l + uu * 64;
        int row = u & 15, head = u >> 4;
        int n = row0 + wv * 16 + row;
        const float* rp = tile + row * 132 + head * 16;
        float4 h0 = *(const float4*)(rp);
        float4 h1 = *(const float4*)(rp + 4);
        float4 h2 = *(const float4*)(rp + 8);
        float4 h3 = *(const float4*)(rp + 12);
        if (h16out) {
            const float4* as4 = (const float4*)(atts + head * 16);
            const float4* ad4 = (const float4*)(attd + head * 16);
            float ss = 0.f, sd = 0.f;
            float4 a, b;
            a = as4[0]; b = ad4[0];
            ss += h0.x*a.x + h0.y*a.y + h0.z*a.z + h0.w*a.w;
            sd += h0.x*b.x + h0.y*b.y + h0.z*b.z + h0.w*b.w;
            a = as4[1]; b = ad4[1];
            ss += h1.x*a.x + h1.y*a.y + h1.z*a.z + h1.w*a.w;
            sd += h1.x*b.x + h1.y*b.y + h1.z*b.z + h1.w*b.w;
            a = as4[2]; b = ad4[2];
            ss += h2.x*a.x + h2.y*a.y + h2.z*a.z + h2.w*a.w;
            sd += h2.x*b.x + h2.y*b.y + h2.z*b.z + h2.w*b.w;
            a = as4[3]; b = ad4[3];
            ss += h3.x*a.x + h3.y*a.y + h3.z*a.z + h3.w*a.w;
            sd += h3.x*b.x + h3.y*b.y + h3.z*b.z + h3.w*b.w;
            al_s[(size_t)n * 8 + head] = ss;
            al_d[(size_t)n * 8 + head] = sd;
            uint4 p0, p1;
            p0.x = (uint)f2bf(h0.x) | ((uint)f2bf(h0.y) << 16);
            p0.y = (uint)f2bf(h0.z) | ((uint)f2bf(h0.w) << 16);
            p0.z = (uint)f2bf(h1.x) | ((uint)f2bf(h1.y) << 16);
            p0.w = (uint)f2bf(h1.z) | ((uint)f2bf(h1.w) << 16);
            p1.x = (uint)f2bf(h2.x) | ((uint)f2bf(h2.y) << 16);
            p1.y = (uint)f2bf(h2.z) | ((uint)f2bf(h2.w) << 16);
            p1.z = (uint)f2bf(h3.x) | ((uint)f2bf(h3.y) << 16);
            p1.w = (uint)f2bf(h3.z) | ((uint)f2bf(h3.w) << 16);
            uint4* dst = (uint4*)((uint*)h16out + (size_t)n * 64 + head * 8);
            dst[0] = p0; dst[1] = p1;
        } else {
            const float4* b4 = (const float4*)(bias + head * 16);
            float4 bb;
            bb = b4[0]; h0.x += bb.x; h0.y += bb.y; h0.z += bb.z; h0.w += bb.w;
            bb = b4[1]; h1.x += bb.x; h1.y += bb.y; h1.z += bb.z; h1.w += bb.w;
            bb = b4[2]; h2.x += bb.x; h2.y += bb.y; h2.z += bb.z; h2.w += bb.w;
            bb = b4[3]; h3.x += bb.x; h3.y += bb.y; h3.z += bb.z; h3.w += bb.w;
            float4* xo = (float4*)(xout + (size_t)n * 128 + head * 16);
            xo[0] = h0; xo[1] = h1; xo[2] = h2; xo[3] = h3;
            uint4 p0, p1;
            p0.x = (uint)f2bf(h0.x) | ((uint)f2bf(h0.y) << 16);
            p0.y = (uint)f2bf(h0.z) | ((uint)f2bf(h0.w) << 16);
            p0.z = (uint)f2bf(h1.x) | ((uint)f2bf(h1.y) << 16);
            p0.w = (uint)f2bf(h1.z) | ((uint)f2bf(h1.w) << 16);
            p1.x = (uint)f2bf(h2.x) | ((uint)f2bf(h2.y) << 16);
            p1.y = (uint)f2bf(h2.z) | ((uint)f2bf(h2.w) << 16);
            p1.z = (uint)f2bf(h3.x) | ((uint)f2bf(h3.y) << 16);
            p1.w = (uint)f2bf(h3.z) | ((uint)f2bf(h3.w) << 16);
            uint4* dst = (uint4*)((uint*)x16out + (size_t)n * 64 + head * 8);
            dst[0] = p0; dst[1] = p1;
        }
    }
}

// ---------------- CSR build (dst-indexed) ----------------
__global__ void k_count(const int* __restrict__ ei, int* __restrict__ deg) {
    int e = blockIdx.x * blockDim.x + threadIdx.x;
    if (e >= ET) return;
    int d = (e < EE) ? ei[EE + e] : (e - EE);
    atomicAdd(&deg[d], 1);
}

__global__ __launch_bounds__(256) void k_scan1(const int* __restrict__ deg,
                                               int* __restrict__ incl,
                                               int* __restrict__ bsum) {
    __shared__ int s[256];
    int t = threadIdx.x;
    int idx = blockIdx.x * 256 + t;
    int v = (idx < NN) ? deg[idx] : 0;
    s[t] = v; __syncthreads();
    for (int off = 1; off < 256; off <<= 1) {
        int u = (t >= off) ? s[t - off] : 0;
        __syncthreads();
        s[t] += u;
        __syncthreads();
    }
    if (idx < NN) incl[idx] = s[t];
    if (t == 255) bsum[blockIdx.x] = s[255];
}

__global__ __launch_bounds__(256) void k_scan2(int* __restrict__ bsum) {
    __shared__ int s[256];
    int t = threadIdx.x;
    int v = (t < NB_SCAN) ? bsum[t] : 0;
    s[t] = v; __syncthreads();
    for (int off = 1; off < 256; off <<= 1) {
        int u = (t >= off) ? s[t - off] : 0;
        __syncthreads();
        s[t] += u;
        __syncthreads();
    }
    if (t < NB_SCAN) bsum[t] = s[t];
}

__global__ __launch_bounds__(256) void k_scan3(const int* __restrict__ deg,
                                               const int* __restrict__ incl,
                                               const int* __restrict__ bsum,
                                               int* __restrict__ rowptr,
                                               int* __restrict__ cursor) {
    int idx = blockIdx.x * 256 + threadIdx.x;
    if (idx >= NN) return;
    int off = (blockIdx.x > 0) ? bsum[blockIdx.x - 1] : 0;
    int inc = incl[idx] + off;
    rowptr[idx + 1] = inc;
    cursor[idx] = inc - deg[idx];
    if (idx == 0) rowptr[0] = 0;
}

__global__ void k_fill(const int* __restrict__ ei,
                       int* __restrict__ cursor, int* __restrict__ col) {
    int e = blockIdx.x * blockDim.x + threadIdx.x;
    if (e >= ET) return;
    int s, d;
    if (e < EE) { s = ei[e]; d = ei[EE + e]; } else { s = d = e - EE; }
    int pos = atomicAdd(&cursor[d], 1);
    col[pos] = s;
}

// ---------------- fused GAT layer ----------------
// one wave per dst node; 4 edges/iter bf16 gather; fused residual+LN+ReLU
__global__ __launch_bounds__(256) void gat_fused(const int* __restrict__ rowptr,
                                                 const int* __restrict__ col,
                                                 const float* __restrict__ al_s,
                                                 const float* __restrict__ al_d,
                                                 const uint* __restrict__ h16,
                                                 const float* __restrict__ bias,
                                                 const float* __restrict__ gamma,
                                                 const float* __restrict__ beta,
                                                 float* __restrict__ x,
                                                 uint* __restrict__ x16u) {
    __shared__ float alph[4][64][8];   // 8 KB
    __shared__ float accv[4][128];     // 2 KB
    int wv = threadIdx.x >> 6;
    int wave = blockIdx.x * 4 + wv;
    int lane = threadIdx.x & 63;
    if (wave >= NN) return;
    const int d = wave;
    const int start = rowptr[d], end = rowptr[d + 1];
    const int deg = end - start;
    const int h8 = lane & 7;
    const int ec = lane >> 3;

    if (deg <= 64) {
        int col_r = 0;
        if (lane < deg) col_r = col[start + lane];
        const float ald = al_d[(size_t)d * 8 + h8];

        float ev[8];
        float mymax = -INFINITY;
        #pragma unroll
        for (int i = 0; i < 8; ++i) {
            int j = ec + 8 * i;
            float v = -INFINITY;
            if (j < deg) {
                int s = __shfl(col_r, j);
                float tt = al_s[(size_t)s * 8 + h8] + ald;
                v = tt >= 0.f ? tt : SLOPE * tt;
            }
            ev[i] = v;
            mymax = fmaxf(mymax, v);
        }
        mymax = fmaxf(mymax, __shfl_xor(mymax, 8));
        mymax = fmaxf(mymax, __shfl_xor(mymax, 16));
        mymax = fmaxf(mymax, __shfl_xor(mymax, 32));

        float dsum = 0.f;
        #pragma unroll
        for (int i = 0; i < 8; ++i) {
            int j = ec + 8 * i;
            float e = __expf(ev[i] - mymax);
            if (j < deg) { alph[wv][j][h8] = e; dsum += e; }
        }
        dsum += __shfl_xor(dsum, 8);
        dsum += __shfl_xor(dsum, 16);
        dsum += __shfl_xor(dsum, 32);
        float rden = 1.f / (dsum + 1e-16f);

        // pass 2: 4 edges per iteration (16 lanes x 8 cols each)
        const int gg = lane >> 4;
        const int cc = lane & 15;
        const int hd2 = cc >> 1;
        float r2v = __shfl(rden, hd2);
        float ac[8] = {0.f, 0.f, 0.f, 0.f, 0.f, 0.f, 0.f, 0.f};
        __asm__ volatile("s_waitcnt lgkmcnt(0)" ::: "memory");
        for (int j = gg; j < deg; j += 4) {
            int s = __shfl(col_r, j);
            float a = alph[wv][j][hd2];
            uint4 hv = *((const uint4*)(h16 + ((size_t)s << 6)) + cc);
            ac[0] += a * bf_lo(hv.x); ac[1] += a * bf_hi(hv.x);
            ac[2] += a * bf_lo(hv.y); ac[3] += a * bf_hi(hv.y);
            ac[4] += a * bf_lo(hv.z); ac[5] += a * bf_hi(hv.z);
            ac[6] += a * bf_lo(hv.w); ac[7] += a * bf_hi(hv.w);
        }
        #pragma unroll
        for (int i = 0; i < 8; ++i) {
            ac[i] += __shfl_xor(ac[i], 16);
            ac[i] += __shfl_xor(ac[i], 32);
        }
        if (gg == 0) {
            #pragma unroll
            for (int i2 = 0; i2 < 4; ++i2)
                *(float2*)&accv[wv][(cc << 3) + (i2 << 1)] =
                    make_float2(ac[2 * i2] * r2v, ac[2 * i2 + 1] * r2v);
        }
    } else {
        // generic fallback (deg > 64)
        const float ald = al_d[(size_t)d * 8 + h8];
        float mymax = -INFINITY;
        for (int e = start + ec; e < end; e += 8) {
            float tt = al_s[(size_t)col[e] * 8 + h8] + ald;
            tt = tt >= 0.f ? tt : SLOPE * tt;
            mymax = fmaxf(mymax, tt);
        }
        mymax = fmaxf(mymax, __shfl_xor(mymax, 8));
        mymax = fmaxf(mymax, __shfl_xor(mymax, 16));
        mymax = fmaxf(mymax, __shfl_xor(mymax, 32));
        float dsum = 0.f;
        for (int e = start + ec; e < end; e += 8) {
            float tt = al_s[(size_t)col[e] * 8 + h8] + ald;
            tt = tt >= 0.f ? tt : SLOPE * tt;
            dsum += __expf(tt - mymax);
        }
        dsum += __shfl_xor(dsum, 8);
        dsum += __shfl_xor(dsum, 16);
        dsum += __shfl_xor(dsum, 32);
        float rden = 1.f / (dsum + 1e-16f);
        const int k5 = lane & 31, g = lane >> 5;
        const int myhead = k5 >> 2;
        float r2 = __shfl(rden, myhead);
        float m2 = __shfl(mymax, myhead);
        float aldh = al_d[(size_t)d * 8 + myhead];
        float a0 = 0.f, a1 = 0.f, a2 = 0.f, a3 = 0.f;
        for (int j2 = g; j2 < deg; j2 += 2) {
            int s = col[start + j2];
            float tt = al_s[(size_t)s * 8 + myhead] + aldh;
            tt = tt >= 0.f ? tt : SLOPE * tt;
            float a = __expf(tt - m2);
            uint2 hv = *((const uint2*)(h16 + ((size_t)s << 6)) + k5);
            a0 += a * bf_lo(hv.x); a1 += a * bf_hi(hv.x);
            a2 += a * bf_lo(hv.y); a3 += a * bf_hi(hv.y);
        }
        a0 *= r2; a1 *= r2; a2 *= r2; a3 *= r2;
        float c0 = a0 + __shfl_xor(a0, 32);
        float c1 = a1 + __shfl_xor(a1, 32);
        float c2 = a2 + __shfl_xor(a2, 32);
        float c3 = a3 + __shfl_xor(a3, 32);
        float accA = g ? c2 : c0;
        float accB = g ? c3 : c1;
        *(float2*)&accv[wv][(k5 << 2) + (g << 1)] = make_float2(accA, accB);
    }

    __asm__ volatile("s_waitcnt lgkmcnt(0)" ::: "memory");
    int colA = lane << 1;
    float2 av = *(const float2*)&accv[wv][colA];
    size_t base = (size_t)d * 128;
    float2 xv = *(const float2*)(x + base + colA);
    float2 bv = *(const float2*)(bias + colA);
    float v0 = xv.x + av.x + bv.x;
    float v1 = xv.y + av.y + bv.y;
    float sum = v0 + v1;
    #pragma unroll
    for (int off = 32; off; off >>= 1) sum += __shfl_xor(sum, off);
    float mu = sum * (1.f / 128.f);
    float d0 = v0 - mu, d1 = v1 - mu;
    float var = d0 * d0 + d1 * d1;
    #pragma unroll
    for (int off = 32; off; off >>= 1) var += __shfl_xor(var, off);
    float inv = rsqrtf(var * (1.f / 128.f) + 1e-5f);
    float2 gv = *(const float2*)(gamma + colA);
    float2 btv = *(const float2*)(beta + colA);
    float o0 = fmaxf((d0 * inv) * gv.x + btv.x, 0.f);
    float o1 = fmaxf((d1 * inv) * gv.y + btv.y, 0.f);
    *(float2*)(x + base + colA) = make_float2(o0, o1);
    x16u[(size_t)d * 64 + lane] = (uint)f2bf(o0) | ((uint)f2bf(o1) << 16);
}

// ---------------- mean pool over sorted batch ----------------
__global__ __launch_bounds__(256) void pool_kernel(const float* __restrict__ x,
                                                   const int* __restrict__ batch,
                                                   float* __restrict__ s,
                                                   float* __restrict__ cnt) {
    __shared__ float acc[2][8][128];
    __shared__ float accc[2][8];
    const int NPB = 250;
    int n0 = blockIdx.x * NPB;
    int nend = min(n0 + NPB, NN);
    int t = threadIdx.x;
    int col = t & 127, grp = t >> 7;
    int b0 = batch[n0];
    int span = batch[nend - 1] - b0 + 1;
    for (int i = t; i < 2 * 8 * 128; i += 256) ((float*)acc)[i] = 0.f;
    if (t < 16) ((float*)accc)[t] = 0.f;
    __syncthreads();
    if (span <= 8) {
        for (int n = n0 + grp; n < nend; n += 2) {
            int b = batch[n] - b0;
            acc[grp][b][col] += x[(size_t)n * 128 + col];
            if (col == 0) accc[grp][b] += 1.f;
        }
        __syncthreads();
        for (int i = t; i < span * 128; i += 256) {
            int b = i >> 7, c = i & 127;
            atomicAdd(&s[(size_t)(b0 + b) * 128 + c], acc[0][b][c] + acc[1][b][c]);
        }
        if (t < span) atomicAdd(&cnt[b0 + t], accc[0][t] + accc[1][t]);
    } else {
        for (int n = n0 + grp; n < nend; n += 2) {
            int b = batch[n];
            atomicAdd(&s[(size_t)b * 128 + col], x[(size_t)n * 128 + col]);
            if (col == 0) atomicAdd(&cnt[b], 1.f);
        }
    }
}

__global__ void finalize_out(const float* __restrict__ s,
                             const float* __restrict__ cnt,
                             float* __restrict__ out) {
    int i = blockIdx.x * blockDim.x + threadIdx.x;
    if (i < GG * DD) out[i] = s[i] / fmaxf(cnt[i >> 7], 1.f);
}

extern "C" void kernel_launch(void* const* d_in, const int* in_sizes, int n_in,
                              void* d_out, int out_size, void* d_ws, size_t ws_size,
                              hipStream_t stream) {
    const float* x_in   = (const float*)d_in[0];
    const int*   ei     = (const int*)d_in[1];
    const int*   batch  = (const int*)d_in[2];
    const float* W_in   = (const float*)d_in[3];
    const float* b_in   = (const float*)d_in[4];
    const float* W_l    = (const float*)d_in[5];
    const float* att_s  = (const float*)d_in[6];
    const float* att_d  = (const float*)d_in[7];
    const float* bias_l = (const float*)d_in[8];
    const float* gamma  = (const float*)d_in[9];
    const float* beta   = (const float*)d_in[10];
    float* out = (float*)d_out;

    float* ws    = (float*)d_ws;
    float* xbuf  = ws;                       // N*128
    float* al_s  = xbuf + (size_t)NN * DD;   // N*8
    float* al_d  = al_s + (size_t)NN * HH;   // N*8
    float* pool  = al_d + (size_t)NN * HH;   // G*128
    float* cnt   = pool + (size_t)GG * DD;   // G
    int*   deg     = (int*)(cnt + GG);       // NN
    int*   incl    = deg + NN;               // NN
    int*   bsum    = incl + NN;              // 256
    int*   rowptr  = bsum + 256;             // NN+1
    int*   cursor  = rowptr + NN + 1;        // NN
    int*   col     = cursor + NN;            // ET
    ushort* x16    = (ushort*)(col + ET);    // N*128
    ushort* h16    = x16 + (size_t)NN * 128; // N*128
    ushort* wt     = h16 + (size_t)NN * 128; // 4*128*128

    // ---- build CSR (dst-indexed) once ----
    hipMemsetAsync(deg, 0, NN * sizeof(int), stream);
    k_count<<<(ET + 255) / 256, 256, 0, stream>>>(ei, deg);
    k_scan1<<<NB_SCAN, 256, 0, stream>>>(deg, incl, bsum);
    k_scan2<<<1, 256, 0, stream>>>(bsum);
    k_scan3<<<NB_SCAN, 256, 0, stream>>>(deg, incl, bsum, rowptr, cursor);
    k_fill<<<(ET + 255) / 256, 256, 0, stream>>>(ei, cursor, col);

    // ---- prep: W^T bf16, x_in bf16 ----
    prep_wt<<<256, 256, 0, stream>>>(W_in, W_l, wt);
    pack_x16<<<5000, 256, 0, stream>>>(x_in, x16);

    // ---- input projection: xbuf = x_in @ W_in + b_in (also refresh x16) ----
    gemm_mfma<<<625, 256, 0, stream>>>(x16, wt, b_in, nullptr, nullptr,
                                       xbuf, x16, nullptr, nullptr, nullptr);

    // ---- 3 GAT layers ----
    for (int l = 0; l < 3; ++l) {
        gemm_mfma<<<625, 256, 0, stream>>>(x16, wt + (size_t)(1 + l) * 16384, nullptr,
                                           att_s + l * 128, att_d + l * 128,
                                           nullptr, nullptr, al_s, al_d, h16);
        gat_fused<<<NN / 4, 256, 0, stream>>>(rowptr, col, al_s, al_d, (const uint*)h16,
                                              bias_l + l * 128, gamma + l * 128, beta + l * 128,
                                              xbuf, (uint*)x16);
    }

    // ---- mean pool ----
    hipMemsetAsync(pool, 0, (size_t)(GG * DD + GG) * sizeof(float), stream);
    pool_kernel<<<160, 256, 0, stream>>>(xbuf, batch, pool, cnt);
    finalize_out<<<(GG * DD + 255) / 256, 256, 0, stream>>>(pool, cnt, out);
}